// Round 17
// baseline (601.211 us; speedup 1.0000x reference)
//
#include <hip/hip_runtime.h>
#include <hip/hip_bf16.h>

#define DIM 256
#define NHEADS 4
#define HDIM 64
#define NPIX 2304          // 48*48
#define NBATCH 8
#define KCN 72             // NPIX/32 key chunks
#define SCALE_L2E 0.18033688011112042f   // 0.125 * log2(e), folded into Q
#define CLAMP_L2E 8.656170245332781f     // 6.0  * log2(e)

typedef __hip_bfloat16 bf16;
typedef __bf16 bf16x8 __attribute__((ext_vector_type(8)));
typedef float  f32x4  __attribute__((ext_vector_type(4)));
typedef float  f32x16 __attribute__((ext_vector_type(16)));

__device__ __forceinline__ unsigned int pack2bf(float a, float b) {
    __hip_bfloat162 h = __float22bfloat162_rn(float2{a, b});
    union { __hip_bfloat162 h; unsigned int u; } c; c.h = h;
    return c.u;
}

// ---- 4 weight matrices (256x256 f32, row-major (m,c)) -> bf16, concatenated.
__global__ __launch_bounds__(256) void cvt_w_kernel(
    const float* __restrict__ w0, const float* __restrict__ w1,
    const float* __restrict__ w2, const float* __restrict__ w3,
    bf16* __restrict__ out)
{
    const int sel = blockIdx.y;
    const float* src = sel == 0 ? w0 : sel == 1 ? w1 : sel == 2 ? w2 : w3;
    const int i = (blockIdx.x * 256 + threadIdx.x) * 8;
    float4 a = *(const float4*)(src + i);
    float4 b = *(const float4*)(src + i + 4);
    uint4 u;
    u.x = pack2bf(a.x, a.y); u.y = pack2bf(a.z, a.w);
    u.z = pack2bf(b.x, b.y); u.w = pack2bf(b.z, b.w);
    *(uint4*)(void*)(out + (size_t)sel * 65536 + i) = u;
}

// ---- src/tgt (b,c,n) f32 -> (b,n,c) bf16 via LDS tile transpose.
__global__ __launch_bounds__(256) void txp_kernel(
    const float* __restrict__ src, const float* __restrict__ tgt,
    bf16* __restrict__ oS, bf16* __restrict__ oT)
{
    const int b = blockIdx.z & 7;
    const float* in = (blockIdx.z >> 3) ? tgt : src;
    bf16* out = (blockIdx.z >> 3) ? oT : oS;
    const int n0 = blockIdx.x * 64, c0 = blockIdx.y * 64;
    __shared__ float tile[64][65];
    const int t = threadIdx.x;
#pragma unroll
    for (int i = 0; i < 4; ++i) {
        int idx = t + i * 256;
        int cl = idx >> 4, n4 = (idx & 15) * 4;
        float4 v = *(const float4*)(in + ((size_t)b * DIM + c0 + cl) * NPIX + n0 + n4);
        tile[cl][n4] = v.x; tile[cl][n4 + 1] = v.y;
        tile[cl][n4 + 2] = v.z; tile[cl][n4 + 3] = v.w;
    }
    __syncthreads();
#pragma unroll
    for (int i = 0; i < 2; ++i) {
        int idx = t + i * 256;
        int nl = idx >> 3, c8 = (idx & 7) * 8;
        uint4 u;
        u.x = pack2bf(tile[c8 + 0][nl], tile[c8 + 1][nl]);
        u.y = pack2bf(tile[c8 + 2][nl], tile[c8 + 3][nl]);
        u.z = pack2bf(tile[c8 + 4][nl], tile[c8 + 5][nl]);
        u.w = pack2bf(tile[c8 + 6][nl], tile[c8 + 7][nl]);
        *(uint4*)(void*)(out + ((size_t)b * NPIX + n0 + nl) * DIM + c0 + c8) = u;
    }
}

// ---- 1x1 conv as MFMA GEMM with register double-buffered K-prefetch.
// D[n][m] = sum_c X[n][c] * W[m][c] + bias[m].
// X: (b,n,c) bf16; W: (m,c) bf16. Block: 64 n x 128 m, 4 waves (16 n each).
// MODE 0: f32 (b,c,n) -> Yf.
// MODE 1: bf16 *scale -> fragment-order QF/KF: [bh][kc][dk][lane][j].
// MODE 2: bf16 -> fragment-order VF: [bh][kc][kb][dt][lane][j].
template <int MODE>
__global__ __launch_bounds__(256) void conv_kernel(
    const bf16* __restrict__ X, const bf16* __restrict__ Wb,
    const float* __restrict__ bias, float scale,
    bf16* __restrict__ Yb, float* __restrict__ Yf)
{
    const int b  = blockIdx.z, mh = blockIdx.y;
    const int n0 = blockIdx.x * 64;
    const int w  = threadIdx.x >> 6, l = threadIdx.x & 63;
    const int lo = l & 15, hi = l >> 4;
    const int nrow = n0 + w * 16 + lo;

    const bf16* xp = X + ((size_t)b * NPIX + nrow) * DIM + hi * 8;
    const bf16* wp = Wb + ((size_t)(mh * 128 + lo)) * DIM + hi * 8;

    f32x4 acc[8];
#pragma unroll
    for (int mt = 0; mt < 8; ++mt) acc[mt] = (f32x4){0.f, 0.f, 0.f, 0.f};

    // preload k0 = 0 fragments
    bf16x8 a = *(const bf16x8*)(const void*)(xp);
    bf16x8 bfr[8];
#pragma unroll
    for (int mt = 0; mt < 8; ++mt)
        bfr[mt] = *(const bf16x8*)(const void*)(wp + (size_t)mt * 16 * DIM);

#pragma unroll
    for (int k0 = 0; k0 < DIM; k0 += 32) {
        bf16x8 a2, bfr2[8];
        const int kn = (k0 + 32) & (DIM - 1);   // wrap: last-iter loads are L1 hits
        a2 = *(const bf16x8*)(const void*)(xp + kn);
#pragma unroll
        for (int mt = 0; mt < 8; ++mt)
            bfr2[mt] = *(const bf16x8*)(const void*)(wp + (size_t)mt * 16 * DIM + kn);
#pragma unroll
        for (int mt = 0; mt < 8; ++mt)
            acc[mt] = __builtin_amdgcn_mfma_f32_16x16x32_bf16(a, bfr[mt], acc[mt], 0, 0, 0);
        a = a2;
#pragma unroll
        for (int mt = 0; mt < 8; ++mt) bfr[mt] = bfr2[mt];
    }

    const int nb = n0 + w * 16 + hi * 4;   // first of 4 consecutive n (rows r)
#pragma unroll
    for (int mt = 0; mt < 8; ++mt) {
        const int m = mh * 128 + mt * 16 + lo;
        const float bv = bias[m];
        if (MODE == 1) {
            const int h = m >> 6, d = m & 63;
            const size_t fb = (((size_t)(b * NHEADS + h) * KCN + (nb >> 5)) * 4 + (d >> 4)) * 512
                            + ((((d >> 3) & 1) * 32) + (nb & 31)) * 8 + (d & 7);
#pragma unroll
            for (int r = 0; r < 4; ++r)
                Yb[fb + r * 8] = __float2bfloat16((acc[mt][r] + bv) * scale);
        } else if (MODE == 2) {
            const int h = m >> 6, dv = m & 63;
            const size_t fb = ((((size_t)(b * NHEADS + h) * KCN + (nb >> 5)) * 2 + ((nb >> 4) & 1)) * 2
                               + (dv >> 5)) * 512
                            + ((((nb >> 3) & 1) * 32) + (dv & 31)) * 8 + (nb & 7);
            uint2 u = make_uint2(pack2bf(acc[mt][0] + bv, acc[mt][1] + bv),
                                 pack2bf(acc[mt][2] + bv, acc[mt][3] + bv));
            *(uint2*)(void*)(Yb + fb) = u;
        } else {
            float4 v = make_float4(acc[mt][0] + bv, acc[mt][1] + bv,
                                   acc[mt][2] + bv, acc[mt][3] + bv);
            *(float4*)(void*)(Yf + ((size_t)b * DIM + m) * NPIX + nb) = v;
        }
    }
}

// ---- MFMA flash attention, 32x32x16, permlane-only cross-lane,
// IN-BLOCK ROUND-ROBIN KEY-SPLIT: 4 waves share one (b,h,64q) tile; wave w
// computes chunks kc = w + 4i (interleaved -> waves stay within an 8KB
// window, preserving per-(b,h) L2 stream sync; per-block traffic unchanged).
// 4x wave count vs R15 => ~4.5 waves/SIMD to hide MFMA/VALU chain latency.
// Depth-1 ping-pong register prefetch; fragment-order operands
// (QF/KF: [bh][kc][dk][64 lanes][8]; VF: [bh][kc][kb][dt][64 lanes][8]).
// Exact cross-wave reduction (disjoint key sets; clamp => no online max).
// Op: (b,n,c) bf16. Grid (36,4,8), block 256.
__global__ __launch_bounds__(256, 4) void attn_kernel(
    const bf16* __restrict__ Qt, const bf16* __restrict__ Kt,
    const bf16* __restrict__ Vt, bf16* __restrict__ Op)
{
    const int b = blockIdx.z, h = blockIdx.y;
    const int w = threadIdx.x >> 6;
    const int l = threadIdx.x & 63;
    const int ln = l & 31, h2 = l >> 5;
    const int nq = blockIdx.x * 64;
    const int bh = b * NHEADS + h;

    __shared__ float redA[64][68];
    __shared__ float redB[64][68];
    __shared__ float lred[4][2][32];

    const bf16* QB = Qt + ((size_t)bh * KCN + blockIdx.x * 2) * 2048 + l * 8;
    const bf16* KB = Kt + (size_t)bh * KCN * 2048 + l * 8;
    const bf16* VB = Vt + (size_t)bh * KCN * 2048 + l * 8;

    // Q B-frags: lane holds Q[q=nq+qs*32+ln][dk*16+h2*8+j] (same for all waves)
    bf16x8 qf[2][4];
#pragma unroll
    for (int qs = 0; qs < 2; ++qs)
#pragma unroll
        for (int dk = 0; dk < 4; ++dk)
            qf[qs][dk] = *(const bf16x8*)(const void*)(QB + qs * 2048 + dk * 512);

    f32x16 oacc[2][2];   // [qs][dt]: O^T[d = dt*32 + row][q]
#pragma unroll
    for (int qs = 0; qs < 2; ++qs)
#pragma unroll
        for (int dt = 0; dt < 2; ++dt)
#pragma unroll
            for (int r = 0; r < 16; ++r) oacc[qs][dt][r] = 0.f;
    float lsum[2] = {0.f, 0.f};

    bf16x8 kfA[4], kfB[4];
    bf16x8 vfA[2][2], vfB[2][2];

    auto load_chunk = [&](int kc_, bf16x8 (&kfD)[4], bf16x8 (&vfD)[2][2]) {
        const bf16* KBn = KB + (size_t)kc_ * 2048;
        const bf16* VBn = VB + (size_t)kc_ * 2048;
#pragma unroll
        for (int dk = 0; dk < 4; ++dk)
            kfD[dk] = *(const bf16x8*)(const void*)(KBn + dk * 512);
#pragma unroll
        for (int kb = 0; kb < 2; ++kb)
#pragma unroll
            for (int dt = 0; dt < 2; ++dt)
                vfD[kb][dt] = *(const bf16x8*)(const void*)(VBn + kb * 1024 + dt * 512);
    };

    auto compute = [&](const bf16x8 (&kfX)[4], const bf16x8 (&vfX)[2][2]) {
#pragma unroll
        for (int qs = 0; qs < 2; ++qs) {
            f32x16 s;
#pragma unroll
            for (int r = 0; r < 16; ++r) s[r] = 0.f;
#pragma unroll
            for (int dk = 0; dk < 4; ++dk)
                s = __builtin_amdgcn_mfma_f32_32x32x16_bf16(kfX[dk], qf[qs][dk], s, 0, 0, 0);

            // P = exp2(clamp(S)); word p covers keys 8*(p>>1)+4*h2+2*(p&1)+{0,1}
            float ls = 0.f;
            unsigned int pk[8];
#pragma unroll
            for (int p = 0; p < 8; ++p) {
                float ea = __builtin_amdgcn_exp2f(
                    __builtin_amdgcn_fmed3f(s[2 * p],     -CLAMP_L2E, CLAMP_L2E));
                float eb = __builtin_amdgcn_exp2f(
                    __builtin_amdgcn_fmed3f(s[2 * p + 1], -CLAMP_L2E, CLAMP_L2E));
                ls += ea + eb;
                pk[p] = pack2bf(ea, eb);
            }
            lsum[qs] += ls;

            // P^T B-frags via half-wave swaps:
            // after swap(a,b): a = {a.lo32 | b.lo32}, b = {a.hi32 | b.hi32}
            unsigned int c00 = pk[0], c02 = pk[2], c01 = pk[1], c03 = pk[3];
            unsigned int c10 = pk[4], c12 = pk[6], c11 = pk[5], c13 = pk[7];
            asm("v_permlane32_swap_b32 %0, %1" : "+v"(c00), "+v"(c02));
            asm("v_permlane32_swap_b32 %0, %1" : "+v"(c01), "+v"(c03));
            asm("v_permlane32_swap_b32 %0, %1" : "+v"(c10), "+v"(c12));
            asm("v_permlane32_swap_b32 %0, %1" : "+v"(c11), "+v"(c13));
            union { unsigned int u[4]; bf16x8 v; } pb0, pb1;
            pb0.u[0] = c00; pb0.u[1] = c01; pb0.u[2] = c02; pb0.u[3] = c03;
            pb1.u[0] = c10; pb1.u[1] = c11; pb1.u[2] = c12; pb1.u[3] = c13;

#pragma unroll
            for (int dt = 0; dt < 2; ++dt) {
                oacc[qs][dt] = __builtin_amdgcn_mfma_f32_32x32x16_bf16(vfX[0][dt], pb0.v, oacc[qs][dt], 0, 0, 0);
                oacc[qs][dt] = __builtin_amdgcn_mfma_f32_32x32x16_bf16(vfX[1][dt], pb1.v, oacc[qs][dt], 0, 0, 0);
            }
        }
    };

    // wave w: chunks w, w+4, ..., w+68 (18 chunks), ping-pong prefetched
    load_chunk(w, kfA, vfA);
    for (int i = 0; i < 18; i += 2) {
        load_chunk(w + 4 * (i + 1), kfB, vfB);
        compute(kfA, vfA);
        load_chunk(i + 2 < 18 ? w + 4 * (i + 2) : w, kfA, vfA);  // wrap: harmless reload
        compute(kfB, vfB);
    }

    // ---- cross-wave reduction (exact: disjoint key sets) ----
#pragma unroll
    for (int qs = 0; qs < 2; ++qs) lsum[qs] += __shfl_xor(lsum[qs], 32);
    if (h2 == 0) { lred[w][0][ln] = lsum[0]; lred[w][1][ln] = lsum[1]; }

    auto writebuf = [&](float (*buf)[68]) {
#pragma unroll
        for (int qs = 0; qs < 2; ++qs)
#pragma unroll
            for (int dt = 0; dt < 2; ++dt)
#pragma unroll
                for (int g = 0; g < 4; ++g) {
                    float4 v = make_float4(oacc[qs][dt][g * 4 + 0], oacc[qs][dt][g * 4 + 1],
                                           oacc[qs][dt][g * 4 + 2], oacc[qs][dt][g * 4 + 3]);
                    *(float4*)&buf[qs * 32 + ln][dt * 32 + g * 8 + h2 * 4] = v;
                }
    };
    auto addbuf = [&](float (*buf)[68]) {
#pragma unroll
        for (int qs = 0; qs < 2; ++qs)
#pragma unroll
            for (int dt = 0; dt < 2; ++dt)
#pragma unroll
                for (int g = 0; g < 4; ++g) {
                    float4 v = *(float4*)&buf[qs * 32 + ln][dt * 32 + g * 8 + h2 * 4];
                    oacc[qs][dt][g * 4 + 0] += v.x; oacc[qs][dt][g * 4 + 1] += v.y;
                    oacc[qs][dt][g * 4 + 2] += v.z; oacc[qs][dt][g * 4 + 3] += v.w;
                }
    };

    if (w == 1) writebuf(redA);
    if (w == 3) writebuf(redB);
    __syncthreads();
    if (w == 0) addbuf(redA);
    if (w == 2) addbuf(redB);
    __syncthreads();
    if (w == 2) writebuf(redA);
    __syncthreads();

    if (w == 0) {
        addbuf(redA);
        float inv[2];
#pragma unroll
        for (int qs = 0; qs < 2; ++qs)
            inv[qs] = 1.f / (lred[0][qs][ln] + lred[1][qs][ln] +
                             lred[2][qs][ln] + lred[3][qs][ln]);
        // store Op (b,n,c): n = nq + qs*32 + ln; c = h*64 + dt*32 + 8*g + 4*h2
#pragma unroll
        for (int qs = 0; qs < 2; ++qs) {
            bf16* rowp = Op + ((size_t)b * NPIX + nq + qs * 32 + ln) * DIM + h * HDIM;
#pragma unroll
            for (int dt = 0; dt < 2; ++dt)
#pragma unroll
                for (int g = 0; g < 4; ++g) {
                    float v0 = oacc[qs][dt][g * 4 + 0] * inv[qs];
                    float v1 = oacc[qs][dt][g * 4 + 1] * inv[qs];
                    float v2 = oacc[qs][dt][g * 4 + 2] * inv[qs];
                    float v3 = oacc[qs][dt][g * 4 + 3] * inv[qs];
                    uint2 u = make_uint2(pack2bf(v0, v1), pack2bf(v2, v3));
                    *(uint2*)(void*)(rowp + dt * 32 + g * 8 + h2 * 4) = u;
                }
        }
    }
}

extern "C" void kernel_launch(void* const* d_in, const int* in_sizes, int n_in,
                              void* d_out, int out_size, void* d_ws, size_t ws_size,
                              hipStream_t stream) {
    const float* src = (const float*)d_in[0];
    const float* tgt = (const float*)d_in[1];
    const float* qw  = (const float*)d_in[2];
    const float* qb  = (const float*)d_in[3];
    const float* kw  = (const float*)d_in[4];
    const float* kb  = (const float*)d_in[5];
    const float* vw  = (const float*)d_in[6];
    const float* vb  = (const float*)d_in[7];
    const float* ow  = (const float*)d_in[8];
    const float* ob  = (const float*)d_in[9];
    float* out = (float*)d_out;

    const size_t TEN = (size_t)NBATCH * DIM * NPIX;  // 4,718,592
    bf16* Wbf  = (bf16*)d_ws;          // 4 x 65536
    bf16* XbfS = Wbf  + 4 * 65536;     // (b,n,c)
    bf16* XbfT = XbfS + TEN;           // (b,n,c)
    bf16* Qt   = XbfT + TEN;           // fragment-order QF, prescaled
    bf16* Kt   = Qt   + TEN;           // fragment-order KF
    bf16* Vt   = Kt   + TEN;           // fragment-order VF
    bf16* Op   = Vt   + TEN;           // (b,n,c)

    cvt_w_kernel<<<dim3(32, 4, 1), 256, 0, stream>>>(qw, kw, vw, ow, Wbf);
    txp_kernel<<<dim3(NPIX / 64, DIM / 64, 2 * NBATCH), 256, 0, stream>>>(src, tgt, XbfS, XbfT);

    dim3 cgrid(NPIX / 64, 2, NBATCH);
    conv_kernel<1><<<cgrid, 256, 0, stream>>>(XbfS, Wbf,             qb, SCALE_L2E, Qt, nullptr);
    conv_kernel<1><<<cgrid, 256, 0, stream>>>(XbfT, Wbf + 1 * 65536, kb, 1.0f,      Kt, nullptr);
    conv_kernel<2><<<cgrid, 256, 0, stream>>>(XbfT, Wbf + 2 * 65536, vb, 1.0f,      Vt, nullptr);

    attn_kernel<<<dim3(NPIX / 64, NHEADS, NBATCH), 256, 0, stream>>>(Qt, Kt, Vt, Op);

    conv_kernel<0><<<cgrid, 256, 0, stream>>>(Op, Wbf + 3 * 65536, ob, 1.0f, nullptr, out);
}

// Round 18
// 206.222 us; speedup vs baseline: 2.9154x; 2.9154x over previous
//
#include <hip/hip_runtime.h>
#include <hip/hip_bf16.h>

#define DIM 256
#define NHEADS 4
#define HDIM 64
#define NPIX 2304          // 48*48
#define NBATCH 8
#define KCN 72             // NPIX/32 key chunks
#define SCALE_L2E 0.18033688011112042f   // 0.125 * log2(e), folded into Q
#define CLAMP_L2E 8.656170245332781f     // 6.0  * log2(e)

typedef __hip_bfloat16 bf16;
typedef __bf16 bf16x8 __attribute__((ext_vector_type(8)));
typedef float  f32x4  __attribute__((ext_vector_type(4)));
typedef float  f32x16 __attribute__((ext_vector_type(16)));

__device__ __forceinline__ unsigned int pack2bf(float a, float b) {
    __hip_bfloat162 h = __float22bfloat162_rn(float2{a, b});
    union { __hip_bfloat162 h; unsigned int u; } c; c.h = h;
    return c.u;
}

// ---- 4 weight matrices (256x256 f32, row-major (m,c)) -> bf16, concatenated.
__global__ __launch_bounds__(256) void cvt_w_kernel(
    const float* __restrict__ w0, const float* __restrict__ w1,
    const float* __restrict__ w2, const float* __restrict__ w3,
    bf16* __restrict__ out)
{
    const int sel = blockIdx.y;
    const float* src = sel == 0 ? w0 : sel == 1 ? w1 : sel == 2 ? w2 : w3;
    const int i = (blockIdx.x * 256 + threadIdx.x) * 8;
    float4 a = *(const float4*)(src + i);
    float4 b = *(const float4*)(src + i + 4);
    uint4 u;
    u.x = pack2bf(a.x, a.y); u.y = pack2bf(a.z, a.w);
    u.z = pack2bf(b.x, b.y); u.w = pack2bf(b.z, b.w);
    *(uint4*)(void*)(out + (size_t)sel * 65536 + i) = u;
}

// ---- src/tgt (b,c,n) f32 -> (b,n,c) bf16 via LDS tile transpose.
__global__ __launch_bounds__(256) void txp_kernel(
    const float* __restrict__ src, const float* __restrict__ tgt,
    bf16* __restrict__ oS, bf16* __restrict__ oT)
{
    const int b = blockIdx.z & 7;
    const float* in = (blockIdx.z >> 3) ? tgt : src;
    bf16* out = (blockIdx.z >> 3) ? oT : oS;
    const int n0 = blockIdx.x * 64, c0 = blockIdx.y * 64;
    __shared__ float tile[64][65];
    const int t = threadIdx.x;
#pragma unroll
    for (int i = 0; i < 4; ++i) {
        int idx = t + i * 256;
        int cl = idx >> 4, n4 = (idx & 15) * 4;
        float4 v = *(const float4*)(in + ((size_t)b * DIM + c0 + cl) * NPIX + n0 + n4);
        tile[cl][n4] = v.x; tile[cl][n4 + 1] = v.y;
        tile[cl][n4 + 2] = v.z; tile[cl][n4 + 3] = v.w;
    }
    __syncthreads();
#pragma unroll
    for (int i = 0; i < 2; ++i) {
        int idx = t + i * 256;
        int nl = idx >> 3, c8 = (idx & 7) * 8;
        uint4 u;
        u.x = pack2bf(tile[c8 + 0][nl], tile[c8 + 1][nl]);
        u.y = pack2bf(tile[c8 + 2][nl], tile[c8 + 3][nl]);
        u.z = pack2bf(tile[c8 + 4][nl], tile[c8 + 5][nl]);
        u.w = pack2bf(tile[c8 + 6][nl], tile[c8 + 7][nl]);
        *(uint4*)(void*)(out + ((size_t)b * NPIX + n0 + nl) * DIM + c0 + c8) = u;
    }
}

// ---- 1x1 conv as MFMA GEMM with register double-buffered K-prefetch.
// D[n][m] = sum_c X[n][c] * W[m][c] + bias[m].
// X: (b,n,c) bf16; W: (m,c) bf16. Block: 64 n x 128 m, 4 waves (16 n each).
// MODE 0: f32 (b,c,n) -> Yf.
// MODE 1: bf16 *scale -> fragment-order QF/KF: [bh][kc][dk][lane][j].
// MODE 2: bf16 -> fragment-order VF: [bh][kc][kb][dt][lane][j].
template <int MODE>
__global__ __launch_bounds__(256) void conv_kernel(
    const bf16* __restrict__ X, const bf16* __restrict__ Wb,
    const float* __restrict__ bias, float scale,
    bf16* __restrict__ Yb, float* __restrict__ Yf)
{
    const int b  = blockIdx.z, mh = blockIdx.y;
    const int n0 = blockIdx.x * 64;
    const int w  = threadIdx.x >> 6, l = threadIdx.x & 63;
    const int lo = l & 15, hi = l >> 4;
    const int nrow = n0 + w * 16 + lo;

    const bf16* xp = X + ((size_t)b * NPIX + nrow) * DIM + hi * 8;
    const bf16* wp = Wb + ((size_t)(mh * 128 + lo)) * DIM + hi * 8;

    f32x4 acc[8];
#pragma unroll
    for (int mt = 0; mt < 8; ++mt) acc[mt] = (f32x4){0.f, 0.f, 0.f, 0.f};

    // preload k0 = 0 fragments
    bf16x8 a = *(const bf16x8*)(const void*)(xp);
    bf16x8 bfr[8];
#pragma unroll
    for (int mt = 0; mt < 8; ++mt)
        bfr[mt] = *(const bf16x8*)(const void*)(wp + (size_t)mt * 16 * DIM);

#pragma unroll
    for (int k0 = 0; k0 < DIM; k0 += 32) {
        bf16x8 a2, bfr2[8];
        const int kn = (k0 + 32) & (DIM - 1);   // wrap: last-iter loads are L1 hits
        a2 = *(const bf16x8*)(const void*)(xp + kn);
#pragma unroll
        for (int mt = 0; mt < 8; ++mt)
            bfr2[mt] = *(const bf16x8*)(const void*)(wp + (size_t)mt * 16 * DIM + kn);
#pragma unroll
        for (int mt = 0; mt < 8; ++mt)
            acc[mt] = __builtin_amdgcn_mfma_f32_16x16x32_bf16(a, bfr[mt], acc[mt], 0, 0, 0);
        a = a2;
#pragma unroll
        for (int mt = 0; mt < 8; ++mt) bfr[mt] = bfr2[mt];
    }

    const int nb = n0 + w * 16 + hi * 4;   // first of 4 consecutive n (rows r)
#pragma unroll
    for (int mt = 0; mt < 8; ++mt) {
        const int m = mh * 128 + mt * 16 + lo;
        const float bv = bias[m];
        if (MODE == 1) {
            const int h = m >> 6, d = m & 63;
            const size_t fb = (((size_t)(b * NHEADS + h) * KCN + (nb >> 5)) * 4 + (d >> 4)) * 512
                            + ((((d >> 3) & 1) * 32) + (nb & 31)) * 8 + (d & 7);
#pragma unroll
            for (int r = 0; r < 4; ++r)
                Yb[fb + r * 8] = __float2bfloat16((acc[mt][r] + bv) * scale);
        } else if (MODE == 2) {
            const int h = m >> 6, dv = m & 63;
            const size_t fb = ((((size_t)(b * NHEADS + h) * KCN + (nb >> 5)) * 2 + ((nb >> 4) & 1)) * 2
                               + (dv >> 5)) * 512
                            + ((((nb >> 3) & 1) * 32) + (dv & 31)) * 8 + (nb & 7);
            uint2 u = make_uint2(pack2bf(acc[mt][0] + bv, acc[mt][1] + bv),
                                 pack2bf(acc[mt][2] + bv, acc[mt][3] + bv));
            *(uint2*)(void*)(Yb + fb) = u;
        } else {
            float4 v = make_float4(acc[mt][0] + bv, acc[mt][1] + bv,
                                   acc[mt][2] + bv, acc[mt][3] + bv);
            *(float4*)(void*)(Yf + ((size_t)b * DIM + m) * NPIX + nb) = v;
        }
    }
}

// ---- MFMA flash attention, 32x32x16, permlane-only cross-lane.
// 4 waves/block = (wq, wk): wave owns ONE 32-q subtile (wq) and HALF the
// key chunks (kc = wk + 2i, 36 chunks, stride-2 interleaved -> both key
// streams stay within one 4KB window; per-block traffic = R15's).
// Halved per-wave state vs R17 (qf 16 + oacc 32 + pingpong 64 ~= 112 regs)
// so launch_bounds(256,3) fits WITHOUT spill (R17 lesson: spill = 1GB scratch).
// Depth-1 ping-pong register prefetch; fragment-order operands
// (QF/KF: [bh][kc][dk][64 lanes][8]; VF: [bh][kc][kb][dt][64 lanes][8]).
// Exact 2-way cross-wave reduction per wq (disjoint key sets, clamp => no max).
// Op: (b,n,c) bf16. Grid (36,4,8), block 256.
__global__ __launch_bounds__(256, 3) void attn_kernel(
    const bf16* __restrict__ Qt, const bf16* __restrict__ Kt,
    const bf16* __restrict__ Vt, bf16* __restrict__ Op)
{
    const int b = blockIdx.z, h = blockIdx.y;
    const int w = threadIdx.x >> 6;
    const int wq = w & 1, wk = w >> 1;
    const int l = threadIdx.x & 63;
    const int ln = l & 31, h2 = l >> 5;
    const int nq = blockIdx.x * 64;
    const int bh = b * NHEADS + h;

    __shared__ float red[2][32][68];
    __shared__ float lred[2][32];

    const bf16* QB = Qt + ((size_t)bh * KCN + blockIdx.x * 2 + wq) * 2048 + l * 8;
    const bf16* KB = Kt + (size_t)bh * KCN * 2048 + l * 8;
    const bf16* VB = Vt + (size_t)bh * KCN * 2048 + l * 8;

    // Q B-frags: lane holds Q[q=nq+wq*32+ln][dk*16+h2*8+j]
    bf16x8 qf[4];
#pragma unroll
    for (int dk = 0; dk < 4; ++dk)
        qf[dk] = *(const bf16x8*)(const void*)(QB + dk * 512);

    f32x16 oacc[2];   // [dt]: O^T[d = dt*32 + row][q]
#pragma unroll
    for (int dt = 0; dt < 2; ++dt)
#pragma unroll
        for (int r = 0; r < 16; ++r) oacc[dt][r] = 0.f;
    float lsum = 0.f;

    bf16x8 kfA[4], kfB[4];
    bf16x8 vfA[2][2], vfB[2][2];

    auto load_chunk = [&](int kc_, bf16x8 (&kfD)[4], bf16x8 (&vfD)[2][2]) {
        const bf16* KBn = KB + (size_t)kc_ * 2048;
        const bf16* VBn = VB + (size_t)kc_ * 2048;
#pragma unroll
        for (int dk = 0; dk < 4; ++dk)
            kfD[dk] = *(const bf16x8*)(const void*)(KBn + dk * 512);
#pragma unroll
        for (int kb = 0; kb < 2; ++kb)
#pragma unroll
            for (int dt = 0; dt < 2; ++dt)
                vfD[kb][dt] = *(const bf16x8*)(const void*)(VBn + kb * 1024 + dt * 512);
    };

    auto compute = [&](const bf16x8 (&kfX)[4], const bf16x8 (&vfX)[2][2]) {
        f32x16 s;
#pragma unroll
        for (int r = 0; r < 16; ++r) s[r] = 0.f;
#pragma unroll
        for (int dk = 0; dk < 4; ++dk)
            s = __builtin_amdgcn_mfma_f32_32x32x16_bf16(kfX[dk], qf[dk], s, 0, 0, 0);

        // P = exp2(clamp(S)); word p covers keys 8*(p>>1)+4*h2+2*(p&1)+{0,1}
        float ls = 0.f;
        unsigned int pk[8];
#pragma unroll
        for (int p = 0; p < 8; ++p) {
            float ea = __builtin_amdgcn_exp2f(
                __builtin_amdgcn_fmed3f(s[2 * p],     -CLAMP_L2E, CLAMP_L2E));
            float eb = __builtin_amdgcn_exp2f(
                __builtin_amdgcn_fmed3f(s[2 * p + 1], -CLAMP_L2E, CLAMP_L2E));
            ls += ea + eb;
            pk[p] = pack2bf(ea, eb);
        }
        lsum += ls;

        // P^T B-frags via half-wave swaps:
        // after swap(a,b): a = {a.lo32 | b.lo32}, b = {a.hi32 | b.hi32}
        unsigned int c00 = pk[0], c02 = pk[2], c01 = pk[1], c03 = pk[3];
        unsigned int c10 = pk[4], c12 = pk[6], c11 = pk[5], c13 = pk[7];
        asm("v_permlane32_swap_b32 %0, %1" : "+v"(c00), "+v"(c02));
        asm("v_permlane32_swap_b32 %0, %1" : "+v"(c01), "+v"(c03));
        asm("v_permlane32_swap_b32 %0, %1" : "+v"(c10), "+v"(c12));
        asm("v_permlane32_swap_b32 %0, %1" : "+v"(c11), "+v"(c13));
        union { unsigned int u[4]; bf16x8 v; } pb0, pb1;
        pb0.u[0] = c00; pb0.u[1] = c01; pb0.u[2] = c02; pb0.u[3] = c03;
        pb1.u[0] = c10; pb1.u[1] = c11; pb1.u[2] = c12; pb1.u[3] = c13;

#pragma unroll
        for (int dt = 0; dt < 2; ++dt) {
            oacc[dt] = __builtin_amdgcn_mfma_f32_32x32x16_bf16(vfX[0][dt], pb0.v, oacc[dt], 0, 0, 0);
            oacc[dt] = __builtin_amdgcn_mfma_f32_32x32x16_bf16(vfX[1][dt], pb1.v, oacc[dt], 0, 0, 0);
        }
    };

    // wave (wq,wk): chunks wk, wk+2, ..., wk+70 (36 chunks), ping-pong prefetched
    load_chunk(wk, kfA, vfA);
    for (int i = 0; i < 36; i += 2) {
        load_chunk(wk + 2 * (i + 1), kfB, vfB);
        compute(kfA, vfA);
        load_chunk(i + 2 < 36 ? wk + 2 * (i + 2) : wk, kfA, vfA);  // wrap: harmless reload
        compute(kfB, vfB);
    }

    // ---- 2-way cross-wave reduction per wq (exact: disjoint key sets) ----
    lsum += __shfl_xor(lsum, 32);
    if (wk == 1) {
        if (h2 == 0) lred[wq][ln] = lsum;
#pragma unroll
        for (int dt = 0; dt < 2; ++dt)
#pragma unroll
            for (int g = 0; g < 4; ++g) {
                float4 v = make_float4(oacc[dt][g * 4 + 0], oacc[dt][g * 4 + 1],
                                       oacc[dt][g * 4 + 2], oacc[dt][g * 4 + 3]);
                *(float4*)&red[wq][ln][dt * 32 + g * 8 + h2 * 4] = v;
            }
    }
    __syncthreads();

    if (wk == 0) {
#pragma unroll
        for (int dt = 0; dt < 2; ++dt)
#pragma unroll
            for (int g = 0; g < 4; ++g) {
                float4 v = *(float4*)&red[wq][ln][dt * 32 + g * 8 + h2 * 4];
                oacc[dt][g * 4 + 0] += v.x; oacc[dt][g * 4 + 1] += v.y;
                oacc[dt][g * 4 + 2] += v.z; oacc[dt][g * 4 + 3] += v.w;
            }
        const float inv = 1.f / (lsum + lred[wq][ln]);

        // store Op (b,n,c): n = nq + wq*32 + ln; c = h*64 + dt*32 + 8*g + 4*h2
        bf16* rowp = Op + ((size_t)b * NPIX + nq + wq * 32 + ln) * DIM + h * HDIM;
#pragma unroll
        for (int dt = 0; dt < 2; ++dt)
#pragma unroll
            for (int g = 0; g < 4; ++g) {
                float v0 = oacc[dt][g * 4 + 0] * inv;
                float v1 = oacc[dt][g * 4 + 1] * inv;
                float v2 = oacc[dt][g * 4 + 2] * inv;
                float v3 = oacc[dt][g * 4 + 3] * inv;
                uint2 u = make_uint2(pack2bf(v0, v1), pack2bf(v2, v3));
                *(uint2*)(void*)(rowp + dt * 32 + g * 8 + h2 * 4) = u;
            }
    }
}

extern "C" void kernel_launch(void* const* d_in, const int* in_sizes, int n_in,
                              void* d_out, int out_size, void* d_ws, size_t ws_size,
                              hipStream_t stream) {
    const float* src = (const float*)d_in[0];
    const float* tgt = (const float*)d_in[1];
    const float* qw  = (const float*)d_in[2];
    const float* qb  = (const float*)d_in[3];
    const float* kw  = (const float*)d_in[4];
    const float* kb  = (const float*)d_in[5];
    const float* vw  = (const float*)d_in[6];
    const float* vb  = (const float*)d_in[7];
    const float* ow  = (const float*)d_in[8];
    const float* ob  = (const float*)d_in[9];
    float* out = (float*)d_out;

    const size_t TEN = (size_t)NBATCH * DIM * NPIX;  // 4,718,592
    bf16* Wbf  = (bf16*)d_ws;          // 4 x 65536
    bf16* XbfS = Wbf  + 4 * 65536;     // (b,n,c)
    bf16* XbfT = XbfS + TEN;           // (b,n,c)
    bf16* Qt   = XbfT + TEN;           // fragment-order QF, prescaled
    bf16* Kt   = Qt   + TEN;           // fragment-order KF
    bf16* Vt   = Kt   + TEN;           // fragment-order VF
    bf16* Op   = Vt   + TEN;           // (b,n,c)

    cvt_w_kernel<<<dim3(32, 4, 1), 256, 0, stream>>>(qw, kw, vw, ow, Wbf);
    txp_kernel<<<dim3(NPIX / 64, DIM / 64, 2 * NBATCH), 256, 0, stream>>>(src, tgt, XbfS, XbfT);

    dim3 cgrid(NPIX / 64, 2, NBATCH);
    conv_kernel<1><<<cgrid, 256, 0, stream>>>(XbfS, Wbf,             qb, SCALE_L2E, Qt, nullptr);
    conv_kernel<1><<<cgrid, 256, 0, stream>>>(XbfT, Wbf + 1 * 65536, kb, 1.0f,      Kt, nullptr);
    conv_kernel<2><<<cgrid, 256, 0, stream>>>(XbfT, Wbf + 2 * 65536, vb, 1.0f,      Vt, nullptr);

    attn_kernel<<<dim3(NPIX / 64, NHEADS, NBATCH), 256, 0, stream>>>(Qt, Kt, Vt, Op);

    conv_kernel<0><<<cgrid, 256, 0, stream>>>(Op, Wbf + 3 * 65536, ob, 1.0f, nullptr, out);
}

// Round 19
// 138.224 us; speedup vs baseline: 4.3495x; 1.4919x over previous
//
#include <hip/hip_runtime.h>
#include <hip/hip_bf16.h>

#define DIM 256
#define NHEADS 4
#define HDIM 64
#define NPIX 2304          // 48*48
#define NBATCH 8
#define KCN 72             // NPIX/32 key chunks
#define NTN 144            // NPIX/16 n-tiles (fragment-order X/Op)
#define SCALE_L2E 0.18033688011112042f   // 0.125 * log2(e), folded into Q
#define CLAMP_L2E 8.656170245332781f     // 6.0  * log2(e)

typedef __hip_bfloat16 bf16;
typedef __bf16 bf16x8 __attribute__((ext_vector_type(8)));
typedef float  f32x4  __attribute__((ext_vector_type(4)));
typedef float  f32x16 __attribute__((ext_vector_type(16)));

__device__ __forceinline__ unsigned int pack2bf(float a, float b) {
    __hip_bfloat162 h = __float22bfloat162_rn(float2{a, b});
    union { __hip_bfloat162 h; unsigned int u; } c; c.h = h;
    return c.u;
}

// ---- 4 weight mats (256x256 f32 row-major (m,c)) -> fragment-order bf16:
// FW[mh][kc][mt][lane=hi*16+lo][j], m = mh*128+mt*16+lo, c = kc*32+hi*8+j.
__global__ __launch_bounds__(256) void cvt_w_kernel(
    const float* __restrict__ w0, const float* __restrict__ w1,
    const float* __restrict__ w2, const float* __restrict__ w3,
    bf16* __restrict__ out)
{
    const int sel = blockIdx.y;
    const float* src = sel == 0 ? w0 : sel == 1 ? w1 : sel == 2 ? w2 : w3;
    const int i = blockIdx.x * 256 + threadIdx.x;   // 8 elems per thread
    const int m = i >> 5, c0 = (i & 31) * 8;
    const int mh = m >> 7, mt = (m >> 4) & 7, lo = m & 15;
    const int kc = c0 >> 5, hi = (c0 >> 3) & 3;
    float4 a = *(const float4*)(src + i * 8);
    float4 b = *(const float4*)(src + i * 8 + 4);
    uint4 u;
    u.x = pack2bf(a.x, a.y); u.y = pack2bf(a.z, a.w);
    u.z = pack2bf(b.x, b.y); u.w = pack2bf(b.z, b.w);
    const size_t fb = (((size_t)(mh * 8 + kc)) * 8 + mt) * 512 + (hi * 16 + lo) * 8;
    *(uint4*)(void*)(out + (size_t)sel * 65536 + fb) = u;
}

// ---- src/tgt (b,c,n) f32 -> fragment-order bf16 FX[b][ntile][kc][lane][j]
// (n = ntile*16 + lo, c = kc*32 + hi*8 + j) via LDS tile transpose.
__global__ __launch_bounds__(256) void txp_kernel(
    const float* __restrict__ src, const float* __restrict__ tgt,
    bf16* __restrict__ oS, bf16* __restrict__ oT)
{
    const int b = blockIdx.z & 7;
    const float* in = (blockIdx.z >> 3) ? tgt : src;
    bf16* out = (blockIdx.z >> 3) ? oT : oS;
    const int n0 = blockIdx.x * 64, c0 = blockIdx.y * 64;
    __shared__ float tile[64][65];
    const int t = threadIdx.x;
#pragma unroll
    for (int i = 0; i < 4; ++i) {
        int idx = t + i * 256;
        int cl = idx >> 4, n4 = (idx & 15) * 4;
        float4 v = *(const float4*)(in + ((size_t)b * DIM + c0 + cl) * NPIX + n0 + n4);
        tile[cl][n4] = v.x; tile[cl][n4 + 1] = v.y;
        tile[cl][n4 + 2] = v.z; tile[cl][n4 + 3] = v.w;
    }
    __syncthreads();
#pragma unroll
    for (int i = 0; i < 2; ++i) {
        int idx = t + i * 256;
        int nl = idx >> 3, c8 = (idx & 7) * 8;
        uint4 u;
        u.x = pack2bf(tile[c8 + 0][nl], tile[c8 + 1][nl]);
        u.y = pack2bf(tile[c8 + 2][nl], tile[c8 + 3][nl]);
        u.z = pack2bf(tile[c8 + 4][nl], tile[c8 + 5][nl]);
        u.w = pack2bf(tile[c8 + 6][nl], tile[c8 + 7][nl]);
        const int n = n0 + nl, c = c0 + c8;
        const size_t fb = (((size_t)(b * NTN + (n >> 4))) * 8 + (c >> 5)) * 512
                        + ((((c >> 3) & 3) * 16) + (n & 15)) * 8;
        *(uint4*)(void*)(out + fb) = u;
    }
}

// ---- 1x1 conv, all operands fragment-order (lane-linear 16B loads), K-SPLIT:
// block = 32n x 128m, 4 waves = (wn, wk); wave: 16n x 128m x K128 (4 kc),
// exact f32 LDS reduce across wk (R18 pattern). Grid (72, 2, 8).
// X: FX[b][ntile][kc][lane][j]; W: FW[mh][kc][mt][lane][j].
// MODE 0: f32 (b,c,n) -> Yf. MODE 1: *scale -> QF/KF frag-order (attn).
// MODE 2: -> VF frag-order (attn).
template <int MODE>
__global__ __launch_bounds__(256, 3) void conv_kernel(
    const bf16* __restrict__ X, const bf16* __restrict__ Wb,
    const float* __restrict__ bias, float scale,
    bf16* __restrict__ Yb, float* __restrict__ Yf)
{
    const int b  = blockIdx.z, mh = blockIdx.y;
    const int n0 = blockIdx.x * 32;
    const int w  = threadIdx.x >> 6, l = threadIdx.x & 63;
    const int wn = w & 1, wk = w >> 1;
    const int lo = l & 15, hi = l >> 4;

    __shared__ float red[2][64][36];   // [wn][lane][32 acc] (pad 36: f4-aligned)

    const int ntile = blockIdx.x * 2 + wn;
    const bf16* xp = X + ((size_t)(b * NTN + ntile) * 8) * 512 + l * 8;
    const bf16* wp = Wb + (size_t)mh * 32768 + l * 8;

    f32x4 acc[8];
#pragma unroll
    for (int mt = 0; mt < 8; ++mt) acc[mt] = (f32x4){0.f, 0.f, 0.f, 0.f};

    const int kbase = wk * 4;
    bf16x8 a = *(const bf16x8*)(const void*)(xp + (size_t)kbase * 512);
    bf16x8 bfr[8];
#pragma unroll
    for (int mt = 0; mt < 8; ++mt)
        bfr[mt] = *(const bf16x8*)(const void*)(wp + (size_t)(kbase * 8 + mt) * 512);

#pragma unroll
    for (int ki = 0; ki < 4; ++ki) {
        const int kn = kbase + ((ki + 1) & 3);   // wrap: harmless L1-hit reload
        bf16x8 a2 = *(const bf16x8*)(const void*)(xp + (size_t)kn * 512);
        bf16x8 bfr2[8];
#pragma unroll
        for (int mt = 0; mt < 8; ++mt)
            bfr2[mt] = *(const bf16x8*)(const void*)(wp + (size_t)(kn * 8 + mt) * 512);
#pragma unroll
        for (int mt = 0; mt < 8; ++mt)
            acc[mt] = __builtin_amdgcn_mfma_f32_16x16x32_bf16(a, bfr[mt], acc[mt], 0, 0, 0);
        a = a2;
#pragma unroll
        for (int mt = 0; mt < 8; ++mt) bfr[mt] = bfr2[mt];
    }

    // ---- exact cross-wave K-reduction ----
    if (wk == 1) {
#pragma unroll
        for (int mt = 0; mt < 8; ++mt)
            *(float4*)&red[wn][l][mt * 4] = make_float4(acc[mt][0], acc[mt][1],
                                                        acc[mt][2], acc[mt][3]);
    }
    __syncthreads();
    if (wk != 0) return;

#pragma unroll
    for (int mt = 0; mt < 8; ++mt) {
        float4 v = *(float4*)&red[wn][l][mt * 4];
        acc[mt][0] += v.x; acc[mt][1] += v.y; acc[mt][2] += v.z; acc[mt][3] += v.w;
    }

    const int nb = n0 + wn * 16 + hi * 4;   // first of 4 consecutive n (rows r)
#pragma unroll
    for (int mt = 0; mt < 8; ++mt) {
        const int m = mh * 128 + mt * 16 + lo;
        const float bv = bias[m];
        if (MODE == 1) {
            const int h = m >> 6, d = m & 63;
            const size_t fb = (((size_t)(b * NHEADS + h) * KCN + (nb >> 5)) * 4 + (d >> 4)) * 512
                            + ((((d >> 3) & 1) * 32) + (nb & 31)) * 8 + (d & 7);
#pragma unroll
            for (int r = 0; r < 4; ++r)
                Yb[fb + r * 8] = __float2bfloat16((acc[mt][r] + bv) * scale);
        } else if (MODE == 2) {
            const int h = m >> 6, dv = m & 63;
            const size_t fb = ((((size_t)(b * NHEADS + h) * KCN + (nb >> 5)) * 2 + ((nb >> 4) & 1)) * 2
                               + (dv >> 5)) * 512
                            + ((((nb >> 3) & 1) * 32) + (dv & 31)) * 8 + (nb & 7);
            uint2 u = make_uint2(pack2bf(acc[mt][0] + bv, acc[mt][1] + bv),
                                 pack2bf(acc[mt][2] + bv, acc[mt][3] + bv));
            *(uint2*)(void*)(Yb + fb) = u;
        } else {
            float4 v = make_float4(acc[mt][0] + bv, acc[mt][1] + bv,
                                   acc[mt][2] + bv, acc[mt][3] + bv);
            *(float4*)(void*)(Yf + ((size_t)b * DIM + m) * NPIX + nb) = v;
        }
    }
}

// ---- MFMA flash attention (R18 structure, unchanged math):
// 4 waves/block = (wq, wk): wave owns one 32-q subtile and half the key
// chunks (kc = wk + 2i). Depth-1 ping-pong register prefetch; fragment-order
// operands; exact 2-way cross-wave reduction per wq.
// CHANGE vs R18: output written FRAGMENT-ORDER FOp[b][ntile][kc][lane][j]
// so the final conv's A-loads are lane-linear. Grid (36,4,8), block 256.
__global__ __launch_bounds__(256, 3) void attn_kernel(
    const bf16* __restrict__ Qt, const bf16* __restrict__ Kt,
    const bf16* __restrict__ Vt, bf16* __restrict__ Op)
{
    const int b = blockIdx.z, h = blockIdx.y;
    const int w = threadIdx.x >> 6;
    const int wq = w & 1, wk = w >> 1;
    const int l = threadIdx.x & 63;
    const int ln = l & 31, h2 = l >> 5;
    const int nq = blockIdx.x * 64;
    const int bh = b * NHEADS + h;

    __shared__ float red[2][32][68];
    __shared__ float lred[2][32];

    const bf16* QB = Qt + ((size_t)bh * KCN + blockIdx.x * 2 + wq) * 2048 + l * 8;
    const bf16* KB = Kt + (size_t)bh * KCN * 2048 + l * 8;
    const bf16* VB = Vt + (size_t)bh * KCN * 2048 + l * 8;

    // Q B-frags: lane holds Q[q=nq+wq*32+ln][dk*16+h2*8+j]
    bf16x8 qf[4];
#pragma unroll
    for (int dk = 0; dk < 4; ++dk)
        qf[dk] = *(const bf16x8*)(const void*)(QB + dk * 512);

    f32x16 oacc[2];   // [dt]: O^T[d = dt*32 + row][q]
#pragma unroll
    for (int dt = 0; dt < 2; ++dt)
#pragma unroll
        for (int r = 0; r < 16; ++r) oacc[dt][r] = 0.f;
    float lsum = 0.f;

    bf16x8 kfA[4], kfB[4];
    bf16x8 vfA[2][2], vfB[2][2];

    auto load_chunk = [&](int kc_, bf16x8 (&kfD)[4], bf16x8 (&vfD)[2][2]) {
        const bf16* KBn = KB + (size_t)kc_ * 2048;
        const bf16* VBn = VB + (size_t)kc_ * 2048;
#pragma unroll
        for (int dk = 0; dk < 4; ++dk)
            kfD[dk] = *(const bf16x8*)(const void*)(KBn + dk * 512);
#pragma unroll
        for (int kb = 0; kb < 2; ++kb)
#pragma unroll
            for (int dt = 0; dt < 2; ++dt)
                vfD[kb][dt] = *(const bf16x8*)(const void*)(VBn + kb * 1024 + dt * 512);
    };

    auto compute = [&](const bf16x8 (&kfX)[4], const bf16x8 (&vfX)[2][2]) {
        f32x16 s;
#pragma unroll
        for (int r = 0; r < 16; ++r) s[r] = 0.f;
#pragma unroll
        for (int dk = 0; dk < 4; ++dk)
            s = __builtin_amdgcn_mfma_f32_32x32x16_bf16(kfX[dk], qf[dk], s, 0, 0, 0);

        // P = exp2(clamp(S)); word p covers keys 8*(p>>1)+4*h2+2*(p&1)+{0,1}
        float ls = 0.f;
        unsigned int pk[8];
#pragma unroll
        for (int p = 0; p < 8; ++p) {
            float ea = __builtin_amdgcn_exp2f(
                __builtin_amdgcn_fmed3f(s[2 * p],     -CLAMP_L2E, CLAMP_L2E));
            float eb = __builtin_amdgcn_exp2f(
                __builtin_amdgcn_fmed3f(s[2 * p + 1], -CLAMP_L2E, CLAMP_L2E));
            ls += ea + eb;
            pk[p] = pack2bf(ea, eb);
        }
        lsum += ls;

        // P^T B-frags via half-wave swaps:
        // after swap(a,b): a = {a.lo32 | b.lo32}, b = {a.hi32 | b.hi32}
        unsigned int c00 = pk[0], c02 = pk[2], c01 = pk[1], c03 = pk[3];
        unsigned int c10 = pk[4], c12 = pk[6], c11 = pk[5], c13 = pk[7];
        asm("v_permlane32_swap_b32 %0, %1" : "+v"(c00), "+v"(c02));
        asm("v_permlane32_swap_b32 %0, %1" : "+v"(c01), "+v"(c03));
        asm("v_permlane32_swap_b32 %0, %1" : "+v"(c10), "+v"(c12));
        asm("v_permlane32_swap_b32 %0, %1" : "+v"(c11), "+v"(c13));
        union { unsigned int u[4]; bf16x8 v; } pb0, pb1;
        pb0.u[0] = c00; pb0.u[1] = c01; pb0.u[2] = c02; pb0.u[3] = c03;
        pb1.u[0] = c10; pb1.u[1] = c11; pb1.u[2] = c12; pb1.u[3] = c13;

#pragma unroll
        for (int dt = 0; dt < 2; ++dt) {
            oacc[dt] = __builtin_amdgcn_mfma_f32_32x32x16_bf16(vfX[0][dt], pb0.v, oacc[dt], 0, 0, 0);
            oacc[dt] = __builtin_amdgcn_mfma_f32_32x32x16_bf16(vfX[1][dt], pb1.v, oacc[dt], 0, 0, 0);
        }
    };

    // wave (wq,wk): chunks wk, wk+2, ..., wk+70 (36 chunks), ping-pong prefetched
    load_chunk(wk, kfA, vfA);
    for (int i = 0; i < 36; i += 2) {
        load_chunk(wk + 2 * (i + 1), kfB, vfB);
        compute(kfA, vfA);
        load_chunk(i + 2 < 36 ? wk + 2 * (i + 2) : wk, kfA, vfA);  // wrap: harmless reload
        compute(kfB, vfB);
    }

    // ---- 2-way cross-wave reduction per wq (exact: disjoint key sets) ----
    lsum += __shfl_xor(lsum, 32);
    if (wk == 1) {
        if (h2 == 0) lred[wq][ln] = lsum;
#pragma unroll
        for (int dt = 0; dt < 2; ++dt)
#pragma unroll
            for (int g = 0; g < 4; ++g) {
                float4 v = make_float4(oacc[dt][g * 4 + 0], oacc[dt][g * 4 + 1],
                                       oacc[dt][g * 4 + 2], oacc[dt][g * 4 + 3]);
                *(float4*)&red[wq][ln][dt * 32 + g * 8 + h2 * 4] = v;
            }
    }
    __syncthreads();

    if (wk == 0) {
#pragma unroll
        for (int dt = 0; dt < 2; ++dt)
#pragma unroll
            for (int g = 0; g < 4; ++g) {
                float4 v = *(float4*)&red[wq][ln][dt * 32 + g * 8 + h2 * 4];
                oacc[dt][g * 4 + 0] += v.x; oacc[dt][g * 4 + 1] += v.y;
                oacc[dt][g * 4 + 2] += v.z; oacc[dt][g * 4 + 3] += v.w;
            }
        const float inv = 1.f / (lsum + lred[wq][ln]);

        // store FOp fragment-order: elem (n = nq+wq*32+ln, c = h*64+dt*32+g*8+h2*4+e)
        // idx = ((b*NTN + (n>>4))*8 + h*2+dt)*512 + (g*16 + (ln&15))*8 + h2*4
        const int ntile = blockIdx.x * 4 + wq * 2 + (ln >> 4);
        bf16* opb = Op + (((size_t)(b * NTN + ntile)) * 8 + h * 2) * 512
                  + (ln & 15) * 8 + h2 * 4;
#pragma unroll
        for (int dt = 0; dt < 2; ++dt)
#pragma unroll
            for (int g = 0; g < 4; ++g) {
                float v0 = oacc[dt][g * 4 + 0] * inv;
                float v1 = oacc[dt][g * 4 + 1] * inv;
                float v2 = oacc[dt][g * 4 + 2] * inv;
                float v3 = oacc[dt][g * 4 + 3] * inv;
                uint2 u = make_uint2(pack2bf(v0, v1), pack2bf(v2, v3));
                *(uint2*)(void*)(opb + (size_t)dt * 512 + g * 128) = u;
            }
    }
}

extern "C" void kernel_launch(void* const* d_in, const int* in_sizes, int n_in,
                              void* d_out, int out_size, void* d_ws, size_t ws_size,
                              hipStream_t stream) {
    const float* src = (const float*)d_in[0];
    const float* tgt = (const float*)d_in[1];
    const float* qw  = (const float*)d_in[2];
    const float* qb  = (const float*)d_in[3];
    const float* kw  = (const float*)d_in[4];
    const float* kb  = (const float*)d_in[5];
    const float* vw  = (const float*)d_in[6];
    const float* vb  = (const float*)d_in[7];
    const float* ow  = (const float*)d_in[8];
    const float* ob  = (const float*)d_in[9];
    float* out = (float*)d_out;

    const size_t TEN = (size_t)NBATCH * DIM * NPIX;  // 4,718,592
    bf16* Wbf  = (bf16*)d_ws;          // 4 x 65536, fragment-order
    bf16* XbfS = Wbf  + 4 * 65536;     // FX[b][ntile][kc][lane][j]
    bf16* XbfT = XbfS + TEN;
    bf16* Qt   = XbfT + TEN;           // fragment-order QF, prescaled
    bf16* Kt   = Qt   + TEN;           // fragment-order KF
    bf16* Vt   = Kt   + TEN;           // fragment-order VF
    bf16* Op   = Vt   + TEN;           // fragment-order FOp

    cvt_w_kernel<<<dim3(32, 4, 1), 256, 0, stream>>>(qw, kw, vw, ow, Wbf);
    txp_kernel<<<dim3(NPIX / 64, DIM / 64, 2 * NBATCH), 256, 0, stream>>>(src, tgt, XbfS, XbfT);

    dim3 cgrid(NPIX / 32, 2, NBATCH);
    conv_kernel<1><<<cgrid, 256, 0, stream>>>(XbfS, Wbf,             qb, SCALE_L2E, Qt, nullptr);
    conv_kernel<1><<<cgrid, 256, 0, stream>>>(XbfT, Wbf + 1 * 65536, kb, 1.0f,      Kt, nullptr);
    conv_kernel<2><<<cgrid, 256, 0, stream>>>(XbfT, Wbf + 2 * 65536, vb, 1.0f,      Vt, nullptr);

    attn_kernel<<<dim3(NPIX / 64, NHEADS, NBATCH), 256, 0, stream>>>(Qt, Kt, Vt, Op);

    conv_kernel<0><<<cgrid, 256, 0, stream>>>(Op, Wbf + 3 * 65536, ob, 1.0f, nullptr, out);
}